// Round 4
// baseline (1972.731 us; speedup 1.0000x reference)
//
#include <hip/hip_runtime.h>
#include <math.h>

// Problem constants
#define B_SZ   16
#define H_SZ   1024
#define W_SZ   1024
#define K_THR  104857u                 // int((1-0.9)*2^20), rank from top
#define TOPK   5

#define EXT_CAP  32768     // per-batch capacity for selected-bin values (~23k expected)
#define CAND_CAP 16384     // per-batch capacity for local-max candidates (~13k expected)

// Wave-task geometry: each wave owns 56 output cols x 16 output rows.
// 19 col-tasks cover 1024 cols (18*56=1008 + 16); 64 strips of 16 rows.
#define STRIP    16
#define KCOLS    19
#define TASKS_PB (64 * KCOLS)          // 1216 tasks per batch
#define BLK_PB   (TASKS_PB / 4)        // 304 blocks per batch (4 waves/block)

// ---------- helpers ----------

__device__ __forceinline__ unsigned sort32(unsigned u) {
    return (u & 0x80000000u) ? ~u : (u | 0x80000000u);
}
__device__ __forceinline__ float unsort32(unsigned u) {
    unsigned v = (u & 0x80000000u) ? (u & 0x7FFFFFFFu) : ~u;
    return __uint_as_float(v);
}

__device__ __forceinline__ void insert5(unsigned long long t[5], unsigned long long key) {
    if (key <= t[4]) return;
    t[4] = key;
#pragma unroll
    for (int i = 4; i > 0; --i) {
        if (t[i] > t[i - 1]) {
            unsigned long long tmp = t[i - 1];
            t[i - 1] = t[i];
            t[i] = tmp;
        }
    }
}

__device__ __forceinline__ void merge5(unsigned long long a[5], const unsigned long long* b) {
    unsigned long long o[5];
    int i = 0, j = 0;
#pragma unroll
    for (int k = 0; k < 5; ++k) {
        unsigned long long av = a[i], bv = b[j];
        if (av >= bv) { o[k] = av; ++i; } else { o[k] = bv; ++j; }
    }
#pragma unroll
    for (int k = 0; k < 5; ++k) a[k] = o[k];
}

// Parallel block-level top-rank select over a histogram h[NBINS] (LDS or global).
// k is the 1-based rank from the TOP. All 256 threads must call.
template <int NBINS>
__device__ __forceinline__ void block_select(const unsigned* h, unsigned k,
                                             unsigned* scratch,
                                             int* out_sel, unsigned* out_c) {
    const int CS = NBINS / 256;
    int t = threadIdx.x;
    unsigned sum = 0;
#pragma unroll
    for (int i = 0; i < CS; ++i) sum += h[t * CS + i];
    scratch[t] = sum;
    __syncthreads();
    // Hillis-Steele inclusive SUFFIX scan: scratch[t] = sum_{j>=t} partial[j]
    for (int d = 1; d < 256; d <<= 1) {
        unsigned v = scratch[t];
        unsigned add = (t + d < 256) ? scratch[t + d] : 0u;
        __syncthreads();
        scratch[t] = v + add;
        __syncthreads();
    }
    unsigned sfx = scratch[t];
    unsigned nxt = (t < 255) ? scratch[t + 1] : 0u;
    if (sfx >= k && nxt < k) {           // unique crossing thread (suffix monotone)
        unsigned c = nxt;
        int sel = t * CS;
        for (int bin = t * CS + CS - 1; bin >= t * CS; --bin) {
            unsigned cnt = h[bin];
            if (c + cnt >= k) { sel = bin; break; }
            c += cnt;
        }
        *out_sel = sel;
        *out_c = c;
    }
    __syncthreads();
}

// ---------- kernels ----------

__global__ __launch_bounds__(256) void zero_kernel(unsigned* p, int n) {
    int i = blockIdx.x * 256 + threadIdx.x;
    if (i < n) p[i] = 0;
}

// Fused pass, wave-centric, LDS-free stencil:
//  - vertical 9-max via van Herk in registers (24 clamped row loads -> 16 col-maxes)
//  - horizontal 9-max via 4 shuffles per row
//  - per-pixel 4096-bin histogram (top 12 bits of sortable float) in LDS
//  - local-max candidates appended to global list (global max is always one)
// Coordinate clamping duplicates in-window values => window max is exact.
__global__ __launch_bounds__(256) void main_kernel(const float* __restrict__ in,
                                                   unsigned* __restrict__ hist,
                                                   unsigned long long* __restrict__ cands,
                                                   unsigned* __restrict__ candcnt) {
    __shared__ unsigned lh[4096];
    int tid = threadIdx.x;
    for (int i = tid; i < 4096; i += 256) lh[i] = 0;

    int bid  = blockIdx.x;
    int b    = bid / BLK_PB;
    int t0   = (bid % BLK_PB) * 4 + (tid >> 6);   // wave task id within batch
    int lane = tid & 63;
    int s    = t0 / KCOLS;                         // row strip
    int k    = t0 % KCOLS;                         // col task
    int r0   = s * STRIP;
    int c0   = k * 56 - 4;
    const float* img = in + ((size_t)b << 20);

    int gx = c0 + lane;
    gx = gx < 0 ? 0 : (gx > 1023 ? 1023 : gx);

    float a[24];
#pragma unroll
    for (int i = 0; i < 24; ++i) {
        int gy = r0 - 4 + i;
        gy = gy < 0 ? 0 : (gy > 1023 ? 1023 : gy);
        a[i] = img[(gy << 10) | gx];
    }

    __syncthreads();          // lh zero visible before atomics

    // Vertical van Herk: cm[o] = max(a[o..o+8]) for o in 0..15.
    float cm[16];
    {
        float S[8], P[8];
        S[7] = a[7];
#pragma unroll
        for (int i = 6; i >= 0; --i) S[i] = fmaxf(a[i], S[i + 1]);
        P[0] = a[8];
#pragma unroll
        for (int j = 1; j < 8; ++j) P[j] = fmaxf(P[j - 1], a[8 + j]);
#pragma unroll
        for (int o = 0; o < 8; ++o) cm[o] = fmaxf(S[o], P[o]);
        S[7] = a[15];
#pragma unroll
        for (int i = 6; i >= 0; --i) S[i] = fmaxf(a[8 + i], S[i + 1]);
        P[0] = a[16];
#pragma unroll
        for (int j = 1; j < 8; ++j) P[j] = fmaxf(P[j - 1], a[16 + j]);
#pragma unroll
        for (int o = 0; o < 8; ++o) cm[8 + o] = fmaxf(S[o], P[o]);
    }

    // Owned output col = c0 + lane, lanes 4..59 (window = lanes lane-4..lane+4).
    int  col      = c0 + lane;
    bool colvalid = (lane >= 4) && (lane < 60) && (col < 1024);

#pragma unroll
    for (int o = 0; o < 16; ++o) {
        float v  = cm[o];
        float w2 = fmaxf(v,  __shfl_down(v, 1));          // cols l..l+1
        float w4 = fmaxf(w2, __shfl_down(w2, 2));         // cols l..l+3
        float up = __shfl_up(w4, 4);                      // cols l-4..l-1
        float dn = __shfl_down(v, 4);                     // col  l+4
        float w9 = fmaxf(fmaxf(up, w4), dn);              // cols l-4..l+4 (9x9 max)
        float vv = a[o + 4];                              // own center value
        if (colvalid) {
            unsigned sbits = sort32(__float_as_uint(vv));
            atomicAdd(&lh[sbits >> 20], 1u);
            if (vv == w9) {                               // >= all 80 neighbors
                unsigned idx = (unsigned)(((r0 + o) << 10) | col);
                unsigned long long key =
                    ((unsigned long long)sbits << 32) | (unsigned)(~idx);
                unsigned pos = atomicAdd(&candcnt[b], 1u);
                if (pos < CAND_CAP) cands[(size_t)b * CAND_CAP + pos] = key;
            }
        }
    }

    __syncthreads();
    unsigned* h = hist + (b << 12);
    for (int i = tid; i < 4096; i += 256) {
        unsigned c = lh[i];
        if (c) atomicAdd(&h[i], c);
    }
}

// Level-1 select: per-batch, find 12-bit bin containing rank K_THR from top.
__global__ __launch_bounds__(256) void selbin_kernel(const unsigned* __restrict__ hist,
                                                     unsigned* __restrict__ selbin,
                                                     unsigned* __restrict__ k2v) {
    __shared__ unsigned scratch[256];
    __shared__ int sel_s;
    __shared__ unsigned c_s;
    int b = blockIdx.x;
    const unsigned* h = hist + (b << 12);
    block_select<4096>(h, K_THR, scratch, &sel_s, &c_s);
    if (threadIdx.x == 0) {
        selbin[b] = (unsigned)sel_s;
        k2v[b]    = K_THR - c_s;
    }
}

// Extract all values (sortable bits) whose top-12 bits == selbin, per batch.
__global__ __launch_bounds__(256) void extract_kernel(const unsigned* __restrict__ in,
                                                      const unsigned* __restrict__ selbin,
                                                      unsigned* __restrict__ ext,
                                                      unsigned* __restrict__ extcnt) {
    __shared__ unsigned buf[4096];
    __shared__ unsigned cnt, base;
    int b = blockIdx.x >> 8;
    unsigned sb = selbin[b];
    if (threadIdx.x == 0) cnt = 0;
    __syncthreads();
    size_t blockbase = (size_t)blockIdx.x * 4096;
#pragma unroll
    for (int i = 0; i < 4; ++i) {
        uint4 v = *(const uint4*)(in + blockbase + (size_t)(i * 256 + threadIdx.x) * 4);
        unsigned s;
        s = sort32(v.x); if ((s >> 20) == sb) buf[atomicAdd(&cnt, 1u)] = s;
        s = sort32(v.y); if ((s >> 20) == sb) buf[atomicAdd(&cnt, 1u)] = s;
        s = sort32(v.z); if ((s >> 20) == sb) buf[atomicAdd(&cnt, 1u)] = s;
        s = sort32(v.w); if ((s >> 20) == sb) buf[atomicAdd(&cnt, 1u)] = s;
    }
    __syncthreads();
    if (threadIdx.x == 0) base = atomicAdd(&extcnt[b], cnt);
    __syncthreads();
    unsigned n = cnt, bs = base;
    for (unsigned i = threadIdx.x; i < n; i += 256) {
        unsigned pos = bs + i;
        if (pos < EXT_CAP) ext[(size_t)b * EXT_CAP + pos] = buf[i];
    }
}

// Resolve remaining 20 bits (12 then 8) among extracted values -> exact thr.
__global__ __launch_bounds__(256) void select23_kernel(const unsigned* __restrict__ ext,
                                                       const unsigned* __restrict__ extcnt,
                                                       const unsigned* __restrict__ selbin,
                                                       const unsigned* __restrict__ k2v,
                                                       float* __restrict__ thr) {
    __shared__ unsigned lh[4096];
    __shared__ unsigned scratch[256];
    __shared__ int sel_s;
    __shared__ unsigned c_s;
    int b = blockIdx.x, tid = threadIdx.x;
    unsigned m = extcnt[b]; if (m > EXT_CAP) m = EXT_CAP;
    const unsigned* e = ext + (size_t)b * EXT_CAP;

    // Level 2: middle 12 bits among extracted values.
    for (int i = tid; i < 4096; i += 256) lh[i] = 0;
    __syncthreads();
    for (unsigned i = tid; i < m; i += 256) atomicAdd(&lh[(e[i] >> 8) & 0xFFFu], 1u);
    __syncthreads();
    unsigned k2 = k2v[b];
    block_select<4096>(lh, k2, scratch, &sel_s, &c_s);
    unsigned sel2 = (unsigned)sel_s;
    unsigned k3 = k2 - c_s;
    __syncthreads();

    // Level 3: low 8 bits among values matching sel2.
    for (int i = tid; i < 256; i += 256) lh[i] = 0;
    __syncthreads();
    for (unsigned i = tid; i < m; i += 256) {
        unsigned s = e[i];
        if (((s >> 8) & 0xFFFu) == sel2) atomicAdd(&lh[s & 0xFFu], 1u);
    }
    __syncthreads();
    block_select<256>(lh, k3, scratch, &sel_s, &c_s);
    if (tid == 0) {
        unsigned bits = (selbin[b] << 20) | (sel2 << 8) | (unsigned)sel_s;
        thr[b] = unsort32(bits);
    }
}

// Final: filter candidates by v > thr, top-5 merge; fallback = max candidate
// key overall (the global argmax is always a local max). Then epilogue.
__global__ __launch_bounds__(256) void final_kernel(const unsigned long long* __restrict__ cands,
                                                    const unsigned* __restrict__ candcnt,
                                                    const float* __restrict__ thr,
                                                    float* __restrict__ out) {
    int b = blockIdx.x, tid = threadIdx.x;
    unsigned n = candcnt[b]; if (n > CAND_CAP) n = CAND_CAP;
    const unsigned long long* cd = cands + (size_t)b * CAND_CAP;
    float th = thr[b];

    unsigned long long t[5] = {0, 0, 0, 0, 0};
    unsigned long long am = 0;
    for (unsigned i = tid; i < n; i += 256) {
        unsigned long long key = cd[i];
        if (key > am) am = key;
        float v = unsort32((unsigned)(key >> 32));
        if (v > th) insert5(t, key);
    }

    __shared__ unsigned long long sh5[256 * 5];
    __shared__ unsigned long long shm[256];
#pragma unroll
    for (int k = 0; k < 5; ++k) sh5[tid * 5 + k] = t[k];
    shm[tid] = am;
    __syncthreads();
    for (int s = 128; s > 0; s >>= 1) {
        if (tid < s) {
            unsigned long long a[5];
#pragma unroll
            for (int k = 0; k < 5; ++k) a[k] = sh5[tid * 5 + k];
            merge5(a, &sh5[(tid + s) * 5]);
#pragma unroll
            for (int k = 0; k < 5; ++k) sh5[tid * 5 + k] = a[k];
            if (shm[tid + s] > shm[tid]) shm[tid] = shm[tid + s];
        }
        __syncthreads();
    }

    if (tid == 0) {
        float topv[5], xs[5], ys[5];
        bool hp[5];
#pragma unroll
        for (int j = 0; j < 5; ++j) {
            unsigned long long key = sh5[j];
            hp[j] = (key != 0ull);
            if (hp[j]) {
                topv[j] = unsort32((unsigned)(key >> 32));
                unsigned idx = ~((unsigned)key);
                xs[j] = (float)(idx & (W_SZ - 1));
                ys[j] = (float)(idx >> 10);
            } else {
                topv[j] = -INFINITY;
                xs[j] = 0.0f;
                ys[j] = 0.0f;
            }
        }
        if (!hp[0]) {                 // fallback: global argmax (first occurrence)
            unsigned idx = ~((unsigned)shm[0]);
            xs[0] = (float)(idx & (W_SZ - 1));
            ys[0] = (float)(idx >> 10);
        }
        float pm = topv[0];
        int nv = 0;
#pragma unroll
        for (int j = 0; j < 5; ++j) {
            bool valid = (topv[j] >= pm * 0.5f) && hp[j];
            nv += valid ? 1 : 0;
        }
        if (nv < 1) nv = 1;
#pragma unroll
        for (int j = 0; j < 5; ++j) {
            bool keep = (j < nv);
            out[b * 10 + j * 2 + 0] = keep ? xs[j] : -1.0f;
            out[b * 10 + j * 2 + 1] = keep ? ys[j] : -1.0f;
            out[160 + b * 5 + j]    = keep ? 1.0f : -1.0f;
        }
    }
}

// ---------- launch ----------

extern "C" void kernel_launch(void* const* d_in, const int* in_sizes, int n_in,
                              void* d_out, int out_size, void* d_ws, size_t ws_size,
                              hipStream_t stream) {
    const float* in = (const float*)d_in[0];
    float* out = (float*)d_out;
    unsigned* w = (unsigned*)d_ws;

    // Zeroed region (contiguous): hist1 | extcnt | candcnt
    unsigned* hist1   = w;                                   // 16*4096 = 65536
    unsigned* extcnt  = w + 65536;                           // 16
    unsigned* candcnt = w + 65552;                           // 16
    // Non-zeroed:
    unsigned* selbin  = w + 65568;                           // 16
    unsigned* k2v     = w + 65584;                           // 16
    float*    thr     = (float*)(w + 65600);                 // 16
    unsigned* ext     = w + 65616;                           // 16*32768 = 524288
    unsigned long long* cands = (unsigned long long*)(w + 65616 + 16 * EXT_CAP);

    zero_kernel<<<257, 256, 0, stream>>>(w, 65568);

    main_kernel<<<16 * BLK_PB, 256, 0, stream>>>(in, hist1, cands, candcnt);
    selbin_kernel<<<16, 256, 0, stream>>>(hist1, selbin, k2v);
    extract_kernel<<<4096, 256, 0, stream>>>((const unsigned*)in, selbin, ext, extcnt);
    select23_kernel<<<16, 256, 0, stream>>>(ext, extcnt, selbin, k2v, thr);
    final_kernel<<<16, 256, 0, stream>>>(cands, candcnt, thr, out);
}

// Round 5
// 304.734 us; speedup vs baseline: 6.4736x; 6.4736x over previous
//
#include <hip/hip_runtime.h>
#include <math.h>

// Problem constants
#define B_SZ   16
#define H_SZ   1024
#define W_SZ   1024
#define K_THR  104857u                 // int((1-0.9)*2^20), rank from top
#define TOPK   5

// Tile geometry
#define TW 64
#define TH 32
#define HALO 4
#define SW 76              // staged row stride (72 data + 4 pad; 76%32=12 -> conflict-free b128)
#define SH 40              // 32 + 2*4
#define HB_SW 68           // hbuf row stride (64 data + 4 pad)

#define EXT_CAP  32768     // per-batch capacity for selected-bin values (~23k expected)
#define CAND_CAP 16384     // per-batch capacity for local-max candidates (~13k expected)
#define CAND_LDS 128       // per-block candidate staging (expect ~25)

// ---------- helpers ----------

__device__ __forceinline__ unsigned sort32(unsigned u) {
    return (u & 0x80000000u) ? ~u : (u | 0x80000000u);
}
__device__ __forceinline__ float unsort32(unsigned u) {
    unsigned v = (u & 0x80000000u) ? (u & 0x7FFFFFFFu) : ~u;
    return __uint_as_float(v);
}

__device__ __forceinline__ void insert5(unsigned long long t[5], unsigned long long key) {
    if (key <= t[4]) return;
    t[4] = key;
#pragma unroll
    for (int i = 4; i > 0; --i) {
        if (t[i] > t[i - 1]) {
            unsigned long long tmp = t[i - 1];
            t[i - 1] = t[i];
            t[i] = tmp;
        }
    }
}

__device__ __forceinline__ void merge5(unsigned long long a[5], const unsigned long long* b) {
    unsigned long long o[5];
    int i = 0, j = 0;
#pragma unroll
    for (int k = 0; k < 5; ++k) {
        unsigned long long av = a[i], bv = b[j];
        if (av >= bv) { o[k] = av; ++i; } else { o[k] = bv; ++j; }
    }
#pragma unroll
    for (int k = 0; k < 5; ++k) a[k] = o[k];
}

// Parallel block-level top-rank select over a histogram h[NBINS] (LDS or global).
// k is the 1-based rank from the TOP. All 256 threads must call.
template <int NBINS>
__device__ __forceinline__ void block_select(const unsigned* h, unsigned k,
                                             unsigned* scratch,
                                             int* out_sel, unsigned* out_c) {
    const int CS = NBINS / 256;
    int t = threadIdx.x;
    unsigned sum = 0;
#pragma unroll
    for (int i = 0; i < CS; ++i) sum += h[t * CS + i];
    scratch[t] = sum;
    __syncthreads();
    // Hillis-Steele inclusive SUFFIX scan: scratch[t] = sum_{j>=t} partial[j]
    for (int d = 1; d < 256; d <<= 1) {
        unsigned v = scratch[t];
        unsigned add = (t + d < 256) ? scratch[t + d] : 0u;
        __syncthreads();
        scratch[t] = v + add;
        __syncthreads();
    }
    unsigned sfx = scratch[t];
    unsigned nxt = (t < 255) ? scratch[t + 1] : 0u;
    if (sfx >= k && nxt < k) {           // unique crossing thread (suffix monotone)
        unsigned c = nxt;
        int sel = t * CS;
        for (int bin = t * CS + CS - 1; bin >= t * CS; --bin) {
            unsigned cnt = h[bin];
            if (c + cnt >= k) { sel = bin; break; }
            c += cnt;
        }
        *out_sel = sel;
        *out_c = c;
    }
    __syncthreads();
}

// ---------- kernels ----------

__global__ __launch_bounds__(256) void zero_kernel(unsigned* p, int n) {
    int i = blockIdx.x * 256 + threadIdx.x;
    if (i < n) p[i] = 0;
}

// Fused pass per 64x32 tile (grid 16*512):
//  P1: float4 global->LDS staging (40x72 data in 40x76 stride)
//  P2: per-pixel 4096-bin histogram (LDS atomics) from center values; flush to global
//  P3: horizontal 9-max into hbuf (OVERLAYS the histogram LDS - lifetimes disjoint)
//  P4: vertical 9-max (van Herk, registers) + candidate collection (LDS staged,
//      ONE global atomic per block)
__global__ __launch_bounds__(256, 2) void main_kernel(const float* __restrict__ in,
                                                      unsigned* __restrict__ hist,
                                                      unsigned long long* __restrict__ cands,
                                                      unsigned* __restrict__ candcnt) {
    __shared__ float stile[SH * SW];          // 12160 B
    __shared__ unsigned overlay[4096];        // 16384 B: lh (P2) then hbuf (P3/P4)
    __shared__ unsigned long long lc[CAND_LDS];
    __shared__ unsigned lcnt, lbase;

    unsigned* lh  = overlay;
    float*   hbuf = (float*)overlay;

    int bid = blockIdx.x;
    int b   = bid >> 9;
    int t   = bid & 511;
    int x0  = (t & 15) << 6;
    int y0  = (t >> 4) << 5;
    int tid = threadIdx.x;
    const float* img = in + ((size_t)b << 20);

    // ---- P1: staging, all float4 (gx = x0 + c4 - 4 is always 0 mod 4, so every
    // float4 is either fully inside the image row or fully outside) ----
    for (int i = tid; i < SH * 18; i += 256) {
        int r  = i / 18;
        int c4 = (i - r * 18) << 2;           // 0,4,...,68
        int gy = y0 + r - HALO;
        int gx = x0 + c4 - HALO;
        float4 v = make_float4(-INFINITY, -INFINITY, -INFINITY, -INFINITY);
        if ((unsigned)gy < (unsigned)H_SZ && (unsigned)gx <= (unsigned)(W_SZ - 4))
            v = *(const float4*)(img + ((size_t)gy << 10) + gx);
        *(float4*)&stile[r * SW + c4] = v;
    }
    for (int i = tid; i < 4096; i += 256) lh[i] = 0;
    if (tid == 0) lcnt = 0;
    __syncthreads();

    // ---- P2: histogram of this tile's 2048 center pixels; keep centers in regs ----
    int c   = tid & 63;
    int r0v = (tid >> 6) << 3;                // output rows r0v..r0v+7
    float vv[8];
#pragma unroll
    for (int o = 0; o < 8; ++o) {
        vv[o] = stile[(r0v + o + HALO) * SW + (c + HALO)];
        atomicAdd(&lh[sort32(__float_as_uint(vv[o])) >> 20], 1u);
    }
    __syncthreads();
    unsigned* hg = hist + (b << 12);
    for (int i = tid; i < 4096; i += 256) {
        unsigned cc = lh[i];
        if (cc) atomicAdd(&hg[i], cc);
    }
    __syncthreads();                          // lh dead; overlay becomes hbuf

    // ---- P3: horizontal 9-max: hbuf[r][c] = max(stile[r][c..c+8]), c in 0..63 ----
    for (int run = tid; run < SH * 8; run += 256) {
        int r  = run >> 3;
        int c0 = (run & 7) << 3;
        const float4* p = (const float4*)&stile[r * SW + c0];
        float4 q0 = p[0], q1 = p[1], q2 = p[2], q3 = p[3];
        float a[16] = {q0.x, q0.y, q0.z, q0.w, q1.x, q1.y, q1.z, q1.w,
                       q2.x, q2.y, q2.z, q2.w, q3.x, q3.y, q3.z, q3.w};
        float S[8], P[8];
        S[7] = a[7];
#pragma unroll
        for (int i = 6; i >= 0; --i) S[i] = fmaxf(a[i], S[i + 1]);
        P[0] = a[8];
#pragma unroll
        for (int j = 1; j < 8; ++j) P[j] = fmaxf(P[j - 1], a[8 + j]);
        float o0[8];
#pragma unroll
        for (int o = 0; o < 8; ++o) o0[o] = fmaxf(S[o], P[o]);
        float4* w = (float4*)&hbuf[r * HB_SW + c0];
        w[0] = make_float4(o0[0], o0[1], o0[2], o0[3]);
        w[1] = make_float4(o0[4], o0[5], o0[6], o0[7]);
    }
    __syncthreads();

    // ---- P4: vertical 9-max over hbuf column c, rows r0v..r0v+15 ----
    float a[16];
#pragma unroll
    for (int i = 0; i < 16; ++i) a[i] = hbuf[(r0v + i) * HB_SW + c];
    float S[8], P[8];
    S[7] = a[7];
#pragma unroll
    for (int i = 6; i >= 0; --i) S[i] = fmaxf(a[i], S[i + 1]);
    P[0] = a[8];
#pragma unroll
    for (int j = 1; j < 8; ++j) P[j] = fmaxf(P[j - 1], a[8 + j]);

#pragma unroll
    for (int o = 0; o < 8; ++o) {
        float w9 = fmaxf(S[o], P[o]);         // 9x9 window max incl. center
        float v  = vv[o];
        if (v == w9) {                        // >= all 80 neighbors
            unsigned sbits = sort32(__float_as_uint(v));
            unsigned idx = (unsigned)(((y0 + r0v + o) << 10) | (x0 + c));
            unsigned long long key =
                ((unsigned long long)sbits << 32) | (unsigned)(~idx);
            unsigned p = atomicAdd(&lcnt, 1u);
            if (p < CAND_LDS) lc[p] = key;
        }
    }
    __syncthreads();

    if (tid == 0) {
        unsigned n = lcnt; if (n > CAND_LDS) n = CAND_LDS;
        lbase = atomicAdd(&candcnt[b], n);
    }
    __syncthreads();
    unsigned n = lcnt; if (n > CAND_LDS) n = CAND_LDS;
    unsigned base = lbase;
    for (unsigned i = tid; i < n; i += 256) {
        unsigned pos = base + i;
        if (pos < CAND_CAP) cands[(size_t)b * CAND_CAP + pos] = lc[i];
    }
}

// Level-1 select: per-batch, find 12-bit bin containing rank K_THR from top.
__global__ __launch_bounds__(256) void selbin_kernel(const unsigned* __restrict__ hist,
                                                     unsigned* __restrict__ selbin,
                                                     unsigned* __restrict__ k2v) {
    __shared__ unsigned scratch[256];
    __shared__ int sel_s;
    __shared__ unsigned c_s;
    int b = blockIdx.x;
    const unsigned* h = hist + (b << 12);
    block_select<4096>(h, K_THR, scratch, &sel_s, &c_s);
    if (threadIdx.x == 0) {
        selbin[b] = (unsigned)sel_s;
        k2v[b]    = K_THR - c_s;
    }
}

// Extract all values (sortable bits) whose top-12 bits == selbin, per batch.
__global__ __launch_bounds__(256) void extract_kernel(const unsigned* __restrict__ in,
                                                      const unsigned* __restrict__ selbin,
                                                      unsigned* __restrict__ ext,
                                                      unsigned* __restrict__ extcnt) {
    __shared__ unsigned buf[4096];
    __shared__ unsigned cnt, base;
    int b = blockIdx.x >> 8;
    unsigned sb = selbin[b];
    if (threadIdx.x == 0) cnt = 0;
    __syncthreads();
    size_t blockbase = (size_t)blockIdx.x * 4096;
#pragma unroll
    for (int i = 0; i < 4; ++i) {
        uint4 v = *(const uint4*)(in + blockbase + (size_t)(i * 256 + threadIdx.x) * 4);
        unsigned s;
        s = sort32(v.x); if ((s >> 20) == sb) buf[atomicAdd(&cnt, 1u)] = s;
        s = sort32(v.y); if ((s >> 20) == sb) buf[atomicAdd(&cnt, 1u)] = s;
        s = sort32(v.z); if ((s >> 20) == sb) buf[atomicAdd(&cnt, 1u)] = s;
        s = sort32(v.w); if ((s >> 20) == sb) buf[atomicAdd(&cnt, 1u)] = s;
    }
    __syncthreads();
    if (threadIdx.x == 0) base = atomicAdd(&extcnt[b], cnt);
    __syncthreads();
    unsigned n = cnt, bs = base;
    for (unsigned i = threadIdx.x; i < n; i += 256) {
        unsigned pos = bs + i;
        if (pos < EXT_CAP) ext[(size_t)b * EXT_CAP + pos] = buf[i];
    }
}

// Resolve remaining 20 bits (12 then 8) among extracted values -> exact thr.
__global__ __launch_bounds__(256) void select23_kernel(const unsigned* __restrict__ ext,
                                                       const unsigned* __restrict__ extcnt,
                                                       const unsigned* __restrict__ selbin,
                                                       const unsigned* __restrict__ k2v,
                                                       float* __restrict__ thr) {
    __shared__ unsigned lh[4096];
    __shared__ unsigned scratch[256];
    __shared__ int sel_s;
    __shared__ unsigned c_s;
    int b = blockIdx.x, tid = threadIdx.x;
    unsigned m = extcnt[b]; if (m > EXT_CAP) m = EXT_CAP;
    const unsigned* e = ext + (size_t)b * EXT_CAP;

    // Level 2: middle 12 bits among extracted values.
    for (int i = tid; i < 4096; i += 256) lh[i] = 0;
    __syncthreads();
    for (unsigned i = tid; i < m; i += 256) atomicAdd(&lh[(e[i] >> 8) & 0xFFFu], 1u);
    __syncthreads();
    unsigned k2 = k2v[b];
    block_select<4096>(lh, k2, scratch, &sel_s, &c_s);
    unsigned sel2 = (unsigned)sel_s;
    unsigned k3 = k2 - c_s;
    __syncthreads();

    // Level 3: low 8 bits among values matching sel2.
    for (int i = tid; i < 256; i += 256) lh[i] = 0;
    __syncthreads();
    for (unsigned i = tid; i < m; i += 256) {
        unsigned s = e[i];
        if (((s >> 8) & 0xFFFu) == sel2) atomicAdd(&lh[s & 0xFFu], 1u);
    }
    __syncthreads();
    block_select<256>(lh, k3, scratch, &sel_s, &c_s);
    if (tid == 0) {
        unsigned bits = (selbin[b] << 20) | (sel2 << 8) | (unsigned)sel_s;
        thr[b] = unsort32(bits);
    }
}

// Final: filter candidates by v > thr, top-5 merge; fallback = max candidate
// key overall (the global argmax is always a local max). Then epilogue.
__global__ __launch_bounds__(256) void final_kernel(const unsigned long long* __restrict__ cands,
                                                    const unsigned* __restrict__ candcnt,
                                                    const float* __restrict__ thr,
                                                    float* __restrict__ out) {
    int b = blockIdx.x, tid = threadIdx.x;
    unsigned n = candcnt[b]; if (n > CAND_CAP) n = CAND_CAP;
    const unsigned long long* cd = cands + (size_t)b * CAND_CAP;
    float th = thr[b];

    unsigned long long t[5] = {0, 0, 0, 0, 0};
    unsigned long long am = 0;
    for (unsigned i = tid; i < n; i += 256) {
        unsigned long long key = cd[i];
        if (key > am) am = key;
        float v = unsort32((unsigned)(key >> 32));
        if (v > th) insert5(t, key);
    }

    __shared__ unsigned long long sh5[256 * 5];
    __shared__ unsigned long long shm[256];
#pragma unroll
    for (int k = 0; k < 5; ++k) sh5[tid * 5 + k] = t[k];
    shm[tid] = am;
    __syncthreads();
    for (int s = 128; s > 0; s >>= 1) {
        if (tid < s) {
            unsigned long long a[5];
#pragma unroll
            for (int k = 0; k < 5; ++k) a[k] = sh5[tid * 5 + k];
            merge5(a, &sh5[(tid + s) * 5]);
#pragma unroll
            for (int k = 0; k < 5; ++k) sh5[tid * 5 + k] = a[k];
            if (shm[tid + s] > shm[tid]) shm[tid] = shm[tid + s];
        }
        __syncthreads();
    }

    if (tid == 0) {
        float topv[5], xs[5], ys[5];
        bool hp[5];
#pragma unroll
        for (int j = 0; j < 5; ++j) {
            unsigned long long key = sh5[j];
            hp[j] = (key != 0ull);
            if (hp[j]) {
                topv[j] = unsort32((unsigned)(key >> 32));
                unsigned idx = ~((unsigned)key);
                xs[j] = (float)(idx & (W_SZ - 1));
                ys[j] = (float)(idx >> 10);
            } else {
                topv[j] = -INFINITY;
                xs[j] = 0.0f;
                ys[j] = 0.0f;
            }
        }
        if (!hp[0]) {                 // fallback: global argmax (first occurrence)
            unsigned idx = ~((unsigned)shm[0]);
            xs[0] = (float)(idx & (W_SZ - 1));
            ys[0] = (float)(idx >> 10);
        }
        float pm = topv[0];
        int nv = 0;
#pragma unroll
        for (int j = 0; j < 5; ++j) {
            bool valid = (topv[j] >= pm * 0.5f) && hp[j];
            nv += valid ? 1 : 0;
        }
        if (nv < 1) nv = 1;
#pragma unroll
        for (int j = 0; j < 5; ++j) {
            bool keep = (j < nv);
            out[b * 10 + j * 2 + 0] = keep ? xs[j] : -1.0f;
            out[b * 10 + j * 2 + 1] = keep ? ys[j] : -1.0f;
            out[160 + b * 5 + j]    = keep ? 1.0f : -1.0f;
        }
    }
}

// ---------- launch ----------

extern "C" void kernel_launch(void* const* d_in, const int* in_sizes, int n_in,
                              void* d_out, int out_size, void* d_ws, size_t ws_size,
                              hipStream_t stream) {
    const float* in = (const float*)d_in[0];
    float* out = (float*)d_out;
    unsigned* w = (unsigned*)d_ws;

    // Zeroed region (contiguous): hist1 | extcnt | candcnt
    unsigned* hist1   = w;                                   // 16*4096 = 65536
    unsigned* extcnt  = w + 65536;                           // 16
    unsigned* candcnt = w + 65552;                           // 16
    // Non-zeroed:
    unsigned* selbin  = w + 65568;                           // 16
    unsigned* k2v     = w + 65584;                           // 16
    float*    thr     = (float*)(w + 65600);                 // 16
    unsigned* ext     = w + 65616;                           // 16*32768 = 524288
    unsigned long long* cands = (unsigned long long*)(w + 65616 + 16 * EXT_CAP);

    zero_kernel<<<257, 256, 0, stream>>>(w, 65568);

    main_kernel<<<8192, 256, 0, stream>>>(in, hist1, cands, candcnt);
    selbin_kernel<<<16, 256, 0, stream>>>(hist1, selbin, k2v);
    extract_kernel<<<4096, 256, 0, stream>>>((const unsigned*)in, selbin, ext, extcnt);
    select23_kernel<<<16, 256, 0, stream>>>(ext, extcnt, selbin, k2v, thr);
    final_kernel<<<16, 256, 0, stream>>>(cands, candcnt, thr, out);
}